// Round 6
// baseline (388.414 us; speedup 1.0000x reference)
//
#include <hip/hip_runtime.h>
#include <hip/hip_bf16.h>
#include <math.h>

#define DD 128
#define QW 896       // 256(Q)+256(K)+256(V)+128(skip)
#define CAP 128

typedef _Float16 f16x8 __attribute__((ext_vector_type(8)));
typedef _Float16 f16x4 __attribute__((ext_vector_type(4)));
typedef _Float16 f16x2 __attribute__((ext_vector_type(2)));
typedef float f32x4 __attribute__((ext_vector_type(4)));

__device__ __forceinline__ float fdot2f(f16x2 a, f16x2 b, float c) {
#if __has_builtin(__builtin_amdgcn_fdot2)
  return __builtin_amdgcn_fdot2(a, b, c, false);
#else
  return fmaf((float)a[0], (float)b[0], fmaf((float)a[1], (float)b[1], c));
#endif
}

// ---------------- CSR build ----------------
__global__ __launch_bounds__(256) void count_kernel(const int* __restrict__ edst,
                                                    int* __restrict__ counts, int E) {
  int e = blockIdx.x * 256 + threadIdx.x;
  if (e < E) atomicAdd(&counts[edst[e]], 1);
}

__global__ __launch_bounds__(1024) void scan_kernel(const int* __restrict__ counts,
                                                    int* __restrict__ offs,
                                                    int* __restrict__ cursor, int Nn) {
  __shared__ int part[1024];
  int tid = threadIdx.x;
  int chunk = (Nn + 1023) >> 10;
  int b = tid * chunk, e = min(b + chunk, Nn);
  int s = 0;
  for (int j = b; j < e; ++j) s += counts[j];
  part[tid] = s;
  __syncthreads();
  for (int d = 1; d < 1024; d <<= 1) {
    int v = (tid >= d) ? part[tid - d] : 0;
    __syncthreads();
    part[tid] += v;
    __syncthreads();
  }
  int excl = tid ? part[tid - 1] : 0;
  for (int j = b; j < e; ++j) { offs[j] = excl; cursor[j] = excl; excl += counts[j]; }
  if (tid == 1023) offs[Nn] = part[1023];
}

__global__ __launch_bounds__(256) void scatter_kernel(const int* __restrict__ edst,
                                                      const int* __restrict__ esrc,
                                                      const int* __restrict__ etyp,
                                                      int* __restrict__ cursor,
                                                      unsigned* __restrict__ epk, int E) {
  int e = blockIdx.x * 256 + threadIdx.x;
  if (e < E) {
    int pos = atomicAdd(&cursor[edst[e]], 1);
    epk[pos] = (unsigned)esrc[e] | ((unsigned)etyp[e] << 18);
  }
}

// ---------------- degree-sorted node order (load balance) ----------------
__global__ __launch_bounds__(256) void degcount_kernel(const int* __restrict__ offs,
                                                       int* __restrict__ dcnt, int Nn) {
  int i = blockIdx.x * 256 + threadIdx.x;
  if (i < Nn) atomicAdd(&dcnt[min(offs[i + 1] - offs[i], 63)], 1);
}

__global__ __launch_bounds__(64) void degscan_kernel(const int* __restrict__ dcnt,
                                                     int* __restrict__ dcur) {
  int t = threadIdx.x;  // 0..63; descending degree: bucket 63 first
  int s = 0;
  for (int d = t + 1; d < 64; ++d) s += dcnt[d];
  dcur[t] = s;
}

__global__ __launch_bounds__(256) void degscatter_kernel(const int* __restrict__ offs,
                                                         int* __restrict__ dcur,
                                                         int* __restrict__ order, int Nn) {
  int i = blockIdx.x * 256 + threadIdx.x;
  if (i < Nn) {
    int pos = atomicAdd(&dcur[min(offs[i + 1] - offs[i], 63)], 1);
    order[pos] = i;
  }
}

// ---------------- pp_cast: all parallel precompute ----------------
__global__ __launch_bounds__(256) void pp_cast(
    const float* __restrict__ Wq, const float* __restrict__ Wk,
    const float* __restrict__ Wv, const float* __restrict__ Wsk,
    const float* __restrict__ bq, const float* __restrict__ bk,
    const float* __restrict__ bv, const float* __restrict__ bsk,
    const float* __restrict__ hemb, const float* __restrict__ We,
    const float* __restrict__ x,
    const float* __restrict__ fw1, const float* __restrict__ fb1,
    const float* __restrict__ fw2, const float* __restrict__ fb2,
    _Float16* __restrict__ WcatT, float* __restrict__ Wcat, float* __restrict__ bcat,
    _Float16* __restrict__ epth, _Float16* __restrict__ xh,
    _Float16* __restrict__ fw1h, _Float16* __restrict__ fw2Th,
    float* __restrict__ bfv, float* __restrict__ bzero, int Nn) {
  int t = blockIdx.x * 256 + threadIdx.x;
  if (t < 256) {  // bfv[l][j]: 512-dot, 4 accumulators
    int l = t >> 7, j = t & 127;
    const float* b1 = fb1 + l * 512;
    const float* w2 = fw2 + (size_t)l * 65536 + j;
    float s0 = fb2[l * 128 + j], s1 = 0.f, s2 = 0.f, s3 = 0.f;
    for (int k = 0; k < 512; k += 4) {
      s0 = fmaf(b1[k], w2[(size_t)k * 128], s0);
      s1 = fmaf(b1[k + 1], w2[(size_t)(k + 1) * 128], s1);
      s2 = fmaf(b1[k + 2], w2[(size_t)(k + 2) * 128], s2);
      s3 = fmaf(b1[k + 3], w2[(size_t)(k + 3) * 128], s3);
    }
    bfv[t] = ((s0 + s1) + (s2 + s3));
    return;
  }
  t -= 256;
  if (t < 2560) {  // eproj
    int ty = t >> 8, col = t & 255;
    float s0 = 0.f, s1 = 0.f, s2 = 0.f, s3 = 0.f;
    const float* hr = hemb + ty * 128;
    for (int c = 0; c < 128; c += 4) {
      s0 = fmaf(hr[c], We[c * 256 + col], s0);
      s1 = fmaf(hr[c + 1], We[(c + 1) * 256 + col], s1);
      s2 = fmaf(hr[c + 2], We[(c + 2) * 256 + col], s2);
      s3 = fmaf(hr[c + 3], We[(c + 3) * 256 + col], s3);
    }
    epth[t] = (_Float16)((s0 + s1) + (s2 + s3));
    return;
  }
  t -= 2560;
  if (t < 114688) {  // WcatT f16 [896][128] + Wcat f32 [128][896]
    int n = t >> 7, k = t & 127;
    float v;
    if (n < 256) v = Wq[k * 256 + n];
    else if (n < 512) v = Wk[k * 256 + (n - 256)];
    else if (n < 768) v = Wv[k * 256 + (n - 512)];
    else v = Wsk[k * 128 + (n - 768)];
    WcatT[t] = (_Float16)v;
    Wcat[k * 896 + n] = v;
    return;
  }
  t -= 114688;
  if (t < 896) {
    float v;
    if (t < 256) v = bq[t];
    else if (t < 512) v = bk[t - 256];
    else if (t < 768) v = bv[t - 512];
    else v = bsk[t - 768];
    bcat[t] = v;
    return;
  }
  t -= 896;
  if (t < 1024) { bzero[t] = 0.f; return; }
  t -= 1024;
  if (t < 16384) {  // fw1 cast, 8/thread
    float4 v0 = *reinterpret_cast<const float4*>(fw1 + (size_t)t * 8);
    float4 v1 = *reinterpret_cast<const float4*>(fw1 + (size_t)t * 8 + 4);
    f16x8 o;
    o[0] = (_Float16)v0.x; o[1] = (_Float16)v0.y; o[2] = (_Float16)v0.z; o[3] = (_Float16)v0.w;
    o[4] = (_Float16)v1.x; o[5] = (_Float16)v1.y; o[6] = (_Float16)v1.z; o[7] = (_Float16)v1.w;
    *reinterpret_cast<f16x8*>(fw1h + (size_t)t * 8) = o;
    return;
  }
  t -= 16384;
  if (t < 131072) {  // fw2 transpose+cast: fw2Th[l][j][k] = fw2[l][k][j]
    int l = t >> 16, rem = t & 65535;
    int j = rem >> 9, k = rem & 511;
    fw2Th[t] = (_Float16)fw2[(size_t)l * 65536 + (size_t)k * 128 + j];
    return;
  }
  t -= 131072;
  if (t < Nn * 16) {  // cast x -> f16, 8/thread
    float4 v0 = *reinterpret_cast<const float4*>(x + (size_t)t * 8);
    float4 v1 = *reinterpret_cast<const float4*>(x + (size_t)t * 8 + 4);
    f16x8 o;
    o[0] = (_Float16)v0.x; o[1] = (_Float16)v0.y; o[2] = (_Float16)v0.z; o[3] = (_Float16)v0.w;
    o[4] = (_Float16)v1.x; o[5] = (_Float16)v1.y; o[6] = (_Float16)v1.z; o[7] = (_Float16)v1.w;
    *reinterpret_cast<f16x8*>(xh + (size_t)t * 8) = o;
  }
}

// ---------------- pp_bmid: bmid = [bfv0 | bfv0@Wcat + bcat] ----------------
__global__ __launch_bounds__(256) void pp_bmid(const float* __restrict__ bfv,
                                               const float* __restrict__ Wcat,
                                               const float* __restrict__ bcat,
                                               float* __restrict__ bmid) {
  int t = blockIdx.x * 256 + threadIdx.x;
  if (t >= 1024) return;
  if (t < 128) { bmid[t] = bfv[t]; return; }
  int n = t - 128;
  float s0 = bcat[n], s1 = 0.f, s2 = 0.f, s3 = 0.f;
  for (int c = 0; c < 128; c += 4) {
    s0 = fmaf(bfv[c], Wcat[c * 896 + n], s0);
    s1 = fmaf(bfv[c + 1], Wcat[(c + 1) * 896 + n], s1);
    s2 = fmaf(bfv[c + 2], Wcat[(c + 2) * 896 + n], s2);
    s3 = fmaf(bfv[c + 3], Wcat[(c + 3) * 896 + n], s3);
  }
  bmid[t] = ((s0 + s1) + (s2 + s3));
}

// ---------------- MFMA f16 GEMM: C = A[M,K] @ Bt[N,K]^T + bias ----------------
// KC>0: compile-time K, fully unrolled (all loads issued up front -> ILP latency hiding).
// Assumes M%128==0, N%128==0, K%32==0.
template <int KC, bool HAS_CF, bool HAS_CH, bool HAS_CHT>
__global__ __launch_bounds__(256) void gemm_tn_f16(const _Float16* __restrict__ A,
                                                   const _Float16* __restrict__ Bt,
                                                   const float* __restrict__ bias,
                                                   float* __restrict__ Cf, int NF,
                                                   _Float16* __restrict__ Ch, int choff, int ldh,
                                                   _Float16* __restrict__ ChT, int ldt,
                                                   int M, int N, int K) {
  const int tid = threadIdx.x;
  const int wid = tid >> 6, lane = tid & 63;
  const int wr = wid >> 1, wc = wid & 1;
  const int il = lane & 15, g = lane >> 4;
  const int row0 = blockIdx.x * 128 + wr * 64;
  const int col0 = blockIdx.y * 128 + wc * 64;
  const _Float16* Ap = A + (size_t)(row0 + il) * K + 8 * g;
  const _Float16* Bp = Bt + (size_t)(col0 + il) * K + 8 * g;
  f32x4 acc[4][4];
#pragma unroll
  for (int a = 0; a < 4; ++a)
#pragma unroll
    for (int b = 0; b < 4; ++b) acc[a][b] = (f32x4){0.f, 0.f, 0.f, 0.f};
  auto kstep = [&](int k0) {
    f16x8 af[4], bf[4];
#pragma unroll
    for (int f = 0; f < 4; ++f) {
      af[f] = *reinterpret_cast<const f16x8*>(Ap + (size_t)(f * 16) * K + k0);
      bf[f] = *reinterpret_cast<const f16x8*>(Bp + (size_t)(f * 16) * K + k0);
    }
#pragma unroll
    for (int fi = 0; fi < 4; ++fi)
#pragma unroll
      for (int fj = 0; fj < 4; ++fj)
        acc[fi][fj] = __builtin_amdgcn_mfma_f32_16x16x32_f16(af[fi], bf[fj], acc[fi][fj], 0, 0, 0);
  };
  if constexpr (KC > 0) {
#pragma unroll
    for (int k0 = 0; k0 < KC; k0 += 32) kstep(k0);
  } else {
    for (int k0 = 0; k0 < K; k0 += 32) kstep(k0);
  }
#pragma unroll
  for (int fj = 0; fj < 4; ++fj) {
    const int col = col0 + fj * 16 + il;
    const float b = bias[col];
#pragma unroll
    for (int fi = 0; fi < 4; ++fi) {
#pragma unroll
      for (int i = 0; i < 4; ++i) {
        const int row = row0 + fi * 16 + g * 4 + i;
        const float v = acc[fi][fj][i] + b;
        if constexpr (HAS_CF) { if (col < NF) Cf[(size_t)row * NF + col] = v; }
        if constexpr (HAS_CH) { if (col >= choff) Ch[(size_t)row * ldh + (col - choff)] = (_Float16)v; }
        if constexpr (HAS_CHT) { ChT[(size_t)col * ldt + row] = (_Float16)v; }
      }
    }
  }
}

// ---------------- fused per-node attention + head-mean + skip + residual + LN -------
// One wave per node (degree-sorted order); 32 lanes per edge, 2 edge slots, prefetch
// depth 2. Lane owns 8 contiguous channels; (lane&31)<16 -> head 0, else head 1.
// Chunk max tracked in registers during QK; exp folded into the V loop.
__global__ __launch_bounds__(256) void node_attn_ln_kernel(
    const _Float16* __restrict__ QKVSh, const _Float16* __restrict__ epth,
    const float* __restrict__ hpre,
    const int* __restrict__ offs, const unsigned* __restrict__ epk,
    const int* __restrict__ order,
    const float* __restrict__ gamma, const float* __restrict__ beta,
    _Float16* __restrict__ hlnh, int Nn) {
  __shared__ float sl0[4][CAP], sl1[4][CAP];
  __shared__ unsigned spk[4][CAP];
  __shared__ float sqe[4][2][10];
  __shared__ __align__(16) _Float16 elds[2560];
  const int tid = threadIdx.x;
  for (int t = tid; t < 1280; t += 256)
    reinterpret_cast<unsigned*>(elds)[t] = reinterpret_cast<const unsigned*>(epth)[t];
  __syncthreads();
  const int w = tid >> 6, lane = tid & 63;
  const int i = order[blockIdx.x * 4 + w];
  const int sub = lane >> 5;     // edge slot 0/1
  const int r = lane & 31;
  const int half = r >> 4;       // head of owned channels
  const int co = r << 3;         // channel offset, 8 ch per lane
  const float scale = 0.08838834764831845f;  // 1/sqrt(128)
  f16x8 qh = *reinterpret_cast<const f16x8*>(QKVSh + (size_t)i * QW + co);
  const f16x2* q2 = reinterpret_cast<const f16x2*>(&qh);
  // prologue: qe[head][ty] = scale * (q_head . e_ty)
#pragma unroll
  for (int ty = 0; ty < 10; ++ty) {
    f16x8 ev = *reinterpret_cast<const f16x8*>(elds + (ty << 8) + co);
    const f16x2* e2 = reinterpret_cast<const f16x2*>(&ev);
    float s = 0.f;
#pragma unroll
    for (int p2 = 0; p2 < 4; ++p2) s = fdot2f(q2[p2], e2[p2], s);
    s += __shfl_xor(s, 1); s += __shfl_xor(s, 2);
    s += __shfl_xor(s, 4); s += __shfl_xor(s, 8);
    if (lane < 32 && (r & 15) == 0) sqe[w][half][ty] = s * scale;
  }
  __threadfence_block();
  float m_me = -1e30f, s_me = 0.f;
  float acc[8] = {0.f};
  const int ebeg = offs[i], eend = offs[i + 1];
  for (int cs = ebeg; cs < eend; cs += CAP) {
    const int cnt = min(CAP, eend - cs);
    const int last = cnt - 1;
    for (int j = lane; j < cnt; j += 64) spk[w][j] = epk[cs + j];
    __threadfence_block();
    // --- QK phase: 2 edges/iter, prefetch depth 2, in-register chunk max ---
    float cmax = -1e30f;
    {
      unsigned pk0 = spk[w][min(sub, last)];
      unsigned pk1 = spk[w][min(2 + sub, last)];
      f16x8 kv0 = *reinterpret_cast<const f16x8*>(QKVSh + (size_t)(pk0 & 0x3FFFF) * QW + 256 + co);
      f16x8 kv1 = *reinterpret_cast<const f16x8*>(QKVSh + (size_t)(pk1 & 0x3FFFF) * QW + 256 + co);
      int ty0 = pk0 >> 18, ty1 = pk1 >> 18;
      for (int j = 0; j < cnt; j += 2) {
        f16x8 kc = kv0;
        const int tyc = ty0;
        kv0 = kv1; ty0 = ty1;
        unsigned pkn = spk[w][min(j + 4 + sub, last)];
        ty1 = pkn >> 18;
        kv1 = *reinterpret_cast<const f16x8*>(QKVSh + (size_t)(pkn & 0x3FFFF) * QW + 256 + co);
        const f16x2* k2 = reinterpret_cast<const f16x2*>(&kc);
        float d = 0.f;
#pragma unroll
        for (int p2 = 0; p2 < 4; ++p2) d = fdot2f(q2[p2], k2[p2], d);
        d += __shfl_xor(d, 1); d += __shfl_xor(d, 2);
        d += __shfl_xor(d, 4); d += __shfl_xor(d, 8);
        d = d * scale + sqe[w][half][tyc];
        if (j + sub < cnt) {
          cmax = fmaxf(cmax, d);
          if ((r & 15) == 0) (half ? sl1 : sl0)[w][j + sub] = d;
        }
      }
    }
    // combine slot maxes (same head at lane^32), rescale running state
    cmax = fmaxf(cmax, __shfl_xor(cmax, 32));
    const float nm = fmaxf(m_me, cmax);
    const float rr = __expf(m_me - nm);
    s_me *= rr;
#pragma unroll
    for (int t = 0; t < 8; ++t) acc[t] *= rr;
    m_me = nm;
    __threadfence_block();
    // --- V phase: 2 edges/iter, prefetch depth 2, exp inline ---
    {
      unsigned pk0 = spk[w][min(sub, last)];
      unsigned pk1 = spk[w][min(2 + sub, last)];
      f16x8 vv0 = *reinterpret_cast<const f16x8*>(QKVSh + (size_t)(pk0 & 0x3FFFF) * QW + 512 + co);
      f16x8 ee0 = *reinterpret_cast<const f16x8*>(elds + ((pk0 >> 18) << 8) + co);
      f16x8 vv1 = *reinterpret_cast<const f16x8*>(QKVSh + (size_t)(pk1 & 0x3FFFF) * QW + 512 + co);
      f16x8 ee1 = *reinterpret_cast<const f16x8*>(elds + ((pk1 >> 18) << 8) + co);
      const float* slme = (half ? sl1 : sl0)[w];
      float ls = 0.f;
      for (int j = 0; j < cnt; j += 2) {
        f16x8 vc = vv0, ec = ee0;
        vv0 = vv1; ee0 = ee1;
        unsigned pkn = spk[w][min(j + 4 + sub, last)];
        vv1 = *reinterpret_cast<const f16x8*>(QKVSh + (size_t)(pkn & 0x3FFFF) * QW + 512 + co);
        ee1 = *reinterpret_cast<const f16x8*>(elds + ((pkn >> 18) << 8) + co);
        const int jc = j + sub;
        float e = 0.f;
        if (jc < cnt) e = __expf(slme[jc] - m_me);
        ls += e;
#pragma unroll
        for (int t = 0; t < 8; ++t) acc[t] = fmaf((float)vc[t] + (float)ec[t], e, acc[t]);
      }
      s_me += ls;
    }
  }
  // combine slots, normalize, head-mean
  const float s_tot = s_me + __shfl_xor(s_me, 32);
  const float invme = 1.f / (s_tot + 1e-16f);
  float g[8];
#pragma unroll
  for (int t = 0; t < 8; ++t) {
    float a = acc[t] + __shfl_xor(acc[t], 32);
    a *= invme;
    g[t] = 0.5f * (a + __shfl_xor(a, 16));
  }
  const int cm = (r & 15) << 3;
  f16x8 sk = *reinterpret_cast<const f16x8*>(QKVSh + (size_t)i * QW + 768 + cm);
  float4 p0 = *reinterpret_cast<const float4*>(hpre + (size_t)i * DD + cm);
  float4 p1 = *reinterpret_cast<const float4*>(hpre + (size_t)i * DD + cm + 4);
  float xv[8];
  xv[0] = g[0] + (float)sk[0] + p0.x; xv[1] = g[1] + (float)sk[1] + p0.y;
  xv[2] = g[2] + (float)sk[2] + p0.z; xv[3] = g[3] + (float)sk[3] + p0.w;
  xv[4] = g[4] + (float)sk[4] + p1.x; xv[5] = g[5] + (float)sk[5] + p1.y;
  xv[6] = g[6] + (float)sk[6] + p1.z; xv[7] = g[7] + (float)sk[7] + p1.w;
  float sm = 0.f;
#pragma unroll
  for (int t = 0; t < 8; ++t) sm += xv[t];
  sm += __shfl_xor(sm, 1); sm += __shfl_xor(sm, 2);
  sm += __shfl_xor(sm, 4); sm += __shfl_xor(sm, 8);
  const float mu = sm * (1.f / 128.f);
  float dx[8], vvs = 0.f;
#pragma unroll
  for (int t = 0; t < 8; ++t) { dx[t] = xv[t] - mu; vvs += dx[t] * dx[t]; }
  vvs += __shfl_xor(vvs, 1); vvs += __shfl_xor(vvs, 2);
  vvs += __shfl_xor(vvs, 4); vvs += __shfl_xor(vvs, 8);
  const float rstd = rsqrtf(vvs * (1.f / 128.f) + 1e-6f);
  if (lane < 16) {
    float4 gm0 = *reinterpret_cast<const float4*>(gamma + cm);
    float4 gm1 = *reinterpret_cast<const float4*>(gamma + cm + 4);
    float4 bt0 = *reinterpret_cast<const float4*>(beta + cm);
    float4 bt1 = *reinterpret_cast<const float4*>(beta + cm + 4);
    f16x8 o;
    o[0] = (_Float16)(dx[0] * rstd * gm0.x + bt0.x);
    o[1] = (_Float16)(dx[1] * rstd * gm0.y + bt0.y);
    o[2] = (_Float16)(dx[2] * rstd * gm0.z + bt0.z);
    o[3] = (_Float16)(dx[3] * rstd * gm0.w + bt0.w);
    o[4] = (_Float16)(dx[4] * rstd * gm1.x + bt1.x);
    o[5] = (_Float16)(dx[5] * rstd * gm1.y + bt1.y);
    o[6] = (_Float16)(dx[6] * rstd * gm1.z + bt1.z);
    o[7] = (_Float16)(dx[7] * rstd * gm1.w + bt1.w);
    *reinterpret_cast<f16x8*>(hlnh + (size_t)i * DD + cm) = o;
  }
}

// ---------------- final: gather mask rows of hln1, apply layer-1 fused FFN ----------------
__global__ __launch_bounds__(128) void final_kernel(const _Float16* __restrict__ hlnh1,
                                                    const float* __restrict__ Wf,
                                                    const float* __restrict__ bfv,
                                                    const int* __restrict__ midx,
                                                    float* __restrict__ out) {
  __shared__ float rowv[128];
  const int b = blockIdx.x, j = threadIdx.x;
  const int row = midx[b];
  rowv[j] = (float)hlnh1[(size_t)row * DD + j];
  __syncthreads();
  const float* w1 = Wf + 16384 + j;  // Wf1[c][j]
  float s = bfv[128 + j];
#pragma unroll 4
  for (int c = 0; c < 128; ++c) s = fmaf(rowv[c], w1[c * 128], s);
  out[b * DD + j] = s;
}

extern "C" void kernel_launch(void* const* d_in, const int* in_sizes, int n_in,
                              void* d_out, int out_size, void* d_ws, size_t ws_size,
                              hipStream_t stream) {
  const float* x    = (const float*)d_in[0];
  const float* hemb = (const float*)d_in[1];
  const float* Wq   = (const float*)d_in[2];
  const float* bq   = (const float*)d_in[3];
  const float* Wk   = (const float*)d_in[4];
  const float* bk   = (const float*)d_in[5];
  const float* Wv   = (const float*)d_in[6];
  const float* bv   = (const float*)d_in[7];
  const float* We   = (const float*)d_in[8];
  const float* Wsk  = (const float*)d_in[9];
  const float* bsk  = (const float*)d_in[10];
  const float* lng  = (const float*)d_in[11];
  const float* lnb  = (const float*)d_in[12];
  const float* fw1  = (const float*)d_in[13];
  const float* fb1  = (const float*)d_in[14];
  const float* fw2  = (const float*)d_in[15];
  const float* fb2  = (const float*)d_in[16];
  const int* eidx   = (const int*)d_in[17];
  const int* etyp   = (const int*)d_in[18];
  const int* midx   = (const int*)d_in[19];

  const int Nn = in_sizes[0] / DD;     // 16000
  const int E = in_sizes[18];          // 256000

  const int* esrc = eidx;
  const int* edst = eidx + E;

  char* p = (char*)d_ws;
  auto alloc = [&](size_t bytes) -> void* {
    void* r = (void*)p;
    p += (bytes + 255) & ~(size_t)255;
    return r;
  };
  _Float16* QKVSh = (_Float16*)alloc((size_t)Nn * QW * 2);
  _Float16* xh    = (_Float16*)alloc((size_t)Nn * DD * 2);
  _Float16* hln0  = (_Float16*)alloc((size_t)Nn * DD * 2);
  _Float16* hln1  = (_Float16*)alloc((size_t)Nn * DD * 2);
  float*    h1    = (float*)alloc((size_t)Nn * DD * 4);
  _Float16* WcatT = (_Float16*)alloc((size_t)QW * DD * 2);
  float*    Wcat  = (float*)alloc((size_t)DD * QW * 4);
  float*    bcat  = (float*)alloc(QW * 4);
  _Float16* epth  = (_Float16*)alloc(2560 * 2);
  _Float16* fw1h  = (_Float16*)alloc((size_t)2 * DD * 512 * 2);
  _Float16* fw2Th = (_Float16*)alloc((size_t)2 * DD * 512 * 2);
  float*    Wf    = (float*)alloc(2 * 128 * 128 * 4);
  _Float16* Wfh   = (_Float16*)alloc(128 * 128 * 2);
  float*    bfv   = (float*)alloc(256 * 4);
  float*    bzero = (float*)alloc(1024 * 4);
  _Float16* BtMid = (_Float16*)alloc((size_t)1024 * 128 * 2);
  float*    bmid  = (float*)alloc(1024 * 4);
  int* counts = (int*)alloc((size_t)Nn * 4);
  int* offs   = (int*)alloc((size_t)(Nn + 1) * 4);
  int* cursor = (int*)alloc((size_t)Nn * 4);
  int* dcnt   = (int*)alloc(64 * 4);
  int* dcur   = (int*)alloc(64 * 4);
  int* order  = (int*)alloc((size_t)Nn * 4);
  unsigned* epk = (unsigned*)alloc((size_t)E * 4);

  // CSR
  hipMemsetAsync(counts, 0, (size_t)Nn * sizeof(int), stream);
  hipMemsetAsync(dcnt, 0, 64 * sizeof(int), stream);
  count_kernel<<<(E + 255) / 256, 256, 0, stream>>>(edst, counts, E);
  scan_kernel<<<1, 1024, 0, stream>>>(counts, offs, cursor, Nn);
  scatter_kernel<<<(E + 255) / 256, 256, 0, stream>>>(edst, esrc, etyp, cursor, epk, E);
  // degree-sorted node order
  degcount_kernel<<<(Nn + 255) / 256, 256, 0, stream>>>(offs, dcnt, Nn);
  degscan_kernel<<<1, 64, 0, stream>>>(dcnt, dcur);
  degscatter_kernel<<<(Nn + 255) / 256, 256, 0, stream>>>(offs, dcur, order, Nn);

  // Precompute
  const int pc_threads = 256 + 2560 + 114688 + 896 + 1024 + 16384 + 131072 + Nn * 16;
  pp_cast<<<(pc_threads + 255) / 256, 256, 0, stream>>>(
      Wq, Wk, Wv, Wsk, bq, bk, bv, bsk, hemb, We, x, fw1, fb1, fw2, fb2,
      WcatT, Wcat, bcat, epth, xh, fw1h, fw2Th, bfv, bzero, Nn);
  pp_bmid<<<4, 256, 0, stream>>>(bfv, Wcat, bcat, bmid);
  // Wf[l] = fw1[l] @ fw2[l] (MFMA); l=0 also emits Wfh + BtMid[0:128] (transposed)
  gemm_tn_f16<0, true, true, true><<<dim3(1, 1), 256, 0, stream>>>(
      fw1h, fw2Th, bzero, Wf, 128, Wfh, 0, 128, BtMid, 128, 128, 128, 512);
  gemm_tn_f16<0, true, false, false><<<dim3(1, 1), 256, 0, stream>>>(
      fw1h + 65536, fw2Th + 65536, bzero, Wf + 16384, 128, nullptr, 0, 0, nullptr, 0,
      128, 128, 512);
  // BtMid[128:1024] = (Wf0 @ Wcat)^T
  gemm_tn_f16<128, false, false, true><<<dim3(1, 7), 256, 0, stream>>>(
      Wfh, WcatT, bzero, nullptr, 0, nullptr, 0, 0, BtMid + 16384, 128, 128, 896, 128);

  // Layer 0
  dim3 g1(Nn / 128, QW / 128);
  gemm_tn_f16<128, false, true, false><<<g1, 256, 0, stream>>>(
      xh, WcatT, bcat, nullptr, 0, QKVSh, 0, QW, nullptr, 0, Nn, QW, DD);
  node_attn_ln_kernel<<<Nn / 4, 256, 0, stream>>>(QKVSh, epth, x, offs, epk, order,
                                                  lng, lnb, hln0, Nn);
  // Fused: [h1 (f32) | QKVS1 (f16)] = hln0 @ [Wf0 | Wf0@Wcat] + bmid
  dim3 g2(Nn / 128, 1024 / 128);
  gemm_tn_f16<128, true, true, false><<<g2, 256, 0, stream>>>(
      hln0, BtMid, bmid, h1, 128, QKVSh, 128, QW, nullptr, 0, Nn, 1024, DD);
  node_attn_ln_kernel<<<Nn / 4, 256, 0, stream>>>(QKVSh, epth, h1, offs, epk, order,
                                                  lng + DD, lnb + DD, hln1, Nn);
  final_kernel<<<64, 128, 0, stream>>>(hln1, Wf, bfv, midx, (float*)d_out);
}

// Round 7
// 319.180 us; speedup vs baseline: 1.2169x; 1.2169x over previous
//
#include <hip/hip_runtime.h>
#include <hip/hip_bf16.h>
#include <math.h>

#define DD 128
#define QW 896       // 256(Q)+256(K)+256(V)+128(skip)
#define CAP 128

typedef _Float16 f16x8 __attribute__((ext_vector_type(8)));
typedef _Float16 f16x2 __attribute__((ext_vector_type(2)));
typedef float f32x4 __attribute__((ext_vector_type(4)));

__device__ __forceinline__ float fdot2f(f16x2 a, f16x2 b, float c) {
#if __has_builtin(__builtin_amdgcn_fdot2)
  return __builtin_amdgcn_fdot2(a, b, c, false);
#else
  return fmaf((float)a[0], (float)b[0], fmaf((float)a[1], (float)b[1], c));
#endif
}

// ---------------- CSR build ----------------
__global__ __launch_bounds__(256) void count_kernel(const int* __restrict__ edst,
                                                    int* __restrict__ counts, int E) {
  int e = blockIdx.x * 256 + threadIdx.x;
  if (e < E) atomicAdd(&counts[edst[e]], 1);
}

// offs/cursor prefix-scan + degree histogram + descending-degree bucket cursors
__global__ __launch_bounds__(1024) void scan_kernel(const int* __restrict__ counts,
                                                    int* __restrict__ offs,
                                                    int* __restrict__ cursor,
                                                    int* __restrict__ dcur, int Nn) {
  __shared__ int part[1024];
  __shared__ int sdcnt[64];
  int tid = threadIdx.x;
  if (tid < 64) sdcnt[tid] = 0;
  int chunk = (Nn + 1023) >> 10;
  int b = tid * chunk, e = min(b + chunk, Nn);
  int s = 0;
  for (int j = b; j < e; ++j) s += counts[j];
  part[tid] = s;
  __syncthreads();
  for (int d = 1; d < 1024; d <<= 1) {
    int v = (tid >= d) ? part[tid - d] : 0;
    __syncthreads();
    part[tid] += v;
    __syncthreads();
  }
  int excl = tid ? part[tid - 1] : 0;
  for (int j = b; j < e; ++j) {
    int c = counts[j];
    offs[j] = excl; cursor[j] = excl; excl += c;
    atomicAdd(&sdcnt[min(c, 63)], 1);
  }
  if (tid == 1023) offs[Nn] = part[1023];
  __syncthreads();
  if (tid < 64) {  // descending degree: bucket 63 first
    int acc = 0;
    for (int d = tid + 1; d < 64; ++d) acc += sdcnt[d];
    dcur[tid] = acc;
  }
}

// pack (src | typ<<18) sorted by dst; also scatter degree-sorted node order
__global__ __launch_bounds__(256) void scatter_kernel(const int* __restrict__ edst,
                                                      const int* __restrict__ esrc,
                                                      const int* __restrict__ etyp,
                                                      int* __restrict__ cursor,
                                                      unsigned* __restrict__ epk,
                                                      const int* __restrict__ offs,
                                                      int* __restrict__ dcur,
                                                      int* __restrict__ order,
                                                      int E, int Nn) {
  int e = blockIdx.x * 256 + threadIdx.x;
  if (e < E) {
    int pos = atomicAdd(&cursor[edst[e]], 1);
    epk[pos] = (unsigned)esrc[e] | ((unsigned)etyp[e] << 18);
  }
  if (e < Nn) {
    int deg = offs[e + 1] - offs[e];
    int pos = atomicAdd(&dcur[min(deg, 63)], 1);
    order[pos] = e;
  }
}

// ---------------- pp_cast: all parallel precompute ----------------
__global__ __launch_bounds__(256) void pp_cast(
    const float* __restrict__ Wq, const float* __restrict__ Wk,
    const float* __restrict__ Wv, const float* __restrict__ Wsk,
    const float* __restrict__ bq, const float* __restrict__ bk,
    const float* __restrict__ bv, const float* __restrict__ bsk,
    const float* __restrict__ hemb, const float* __restrict__ We,
    const float* __restrict__ x,
    const float* __restrict__ fw1, const float* __restrict__ fb1,
    const float* __restrict__ fw2, const float* __restrict__ fb2,
    _Float16* __restrict__ WcatT, float* __restrict__ Wcat, float* __restrict__ bcat,
    _Float16* __restrict__ epth, _Float16* __restrict__ xh,
    _Float16* __restrict__ fw1h,
    float* __restrict__ bfv, float* __restrict__ bzero, int Nn) {
  int t = blockIdx.x * 256 + threadIdx.x;
  if (t < 256) {  // bfv[l][j]: 512-dot, 4 accumulators
    int l = t >> 7, j = t & 127;
    const float* b1 = fb1 + l * 512;
    const float* w2 = fw2 + (size_t)l * 65536 + j;
    float s0 = fb2[l * 128 + j], s1 = 0.f, s2 = 0.f, s3 = 0.f;
    for (int k = 0; k < 512; k += 4) {
      s0 = fmaf(b1[k], w2[(size_t)k * 128], s0);
      s1 = fmaf(b1[k + 1], w2[(size_t)(k + 1) * 128], s1);
      s2 = fmaf(b1[k + 2], w2[(size_t)(k + 2) * 128], s2);
      s3 = fmaf(b1[k + 3], w2[(size_t)(k + 3) * 128], s3);
    }
    bfv[t] = ((s0 + s1) + (s2 + s3));
    return;
  }
  t -= 256;
  if (t < 2560) {  // eproj
    int ty = t >> 8, col = t & 255;
    float s0 = 0.f, s1 = 0.f, s2 = 0.f, s3 = 0.f;
    const float* hr = hemb + ty * 128;
    for (int c = 0; c < 128; c += 4) {
      s0 = fmaf(hr[c], We[c * 256 + col], s0);
      s1 = fmaf(hr[c + 1], We[(c + 1) * 256 + col], s1);
      s2 = fmaf(hr[c + 2], We[(c + 2) * 256 + col], s2);
      s3 = fmaf(hr[c + 3], We[(c + 3) * 256 + col], s3);
    }
    epth[t] = (_Float16)((s0 + s1) + (s2 + s3));
    return;
  }
  t -= 2560;
  if (t < 114688) {  // WcatT f16 [896][128] + Wcat f32 [128][896]
    int n = t >> 7, k = t & 127;
    float v;
    if (n < 256) v = Wq[k * 256 + n];
    else if (n < 512) v = Wk[k * 256 + (n - 256)];
    else if (n < 768) v = Wv[k * 256 + (n - 512)];
    else v = Wsk[k * 128 + (n - 768)];
    WcatT[t] = (_Float16)v;
    Wcat[k * 896 + n] = v;
    return;
  }
  t -= 114688;
  if (t < 896) {
    float v;
    if (t < 256) v = bq[t];
    else if (t < 512) v = bk[t - 256];
    else if (t < 768) v = bv[t - 512];
    else v = bsk[t - 768];
    bcat[t] = v;
    return;
  }
  t -= 896;
  if (t < 1024) { bzero[t] = 0.f; return; }
  t -= 1024;
  if (t < 16384) {  // fw1 cast, 8/thread
    float4 v0 = *reinterpret_cast<const float4*>(fw1 + (size_t)t * 8);
    float4 v1 = *reinterpret_cast<const float4*>(fw1 + (size_t)t * 8 + 4);
    f16x8 o;
    o[0] = (_Float16)v0.x; o[1] = (_Float16)v0.y; o[2] = (_Float16)v0.z; o[3] = (_Float16)v0.w;
    o[4] = (_Float16)v1.x; o[5] = (_Float16)v1.y; o[6] = (_Float16)v1.z; o[7] = (_Float16)v1.w;
    *reinterpret_cast<f16x8*>(fw1h + (size_t)t * 8) = o;
    return;
  }
  t -= 16384;
  if (t < Nn * 16) {  // cast x -> f16, 8/thread
    float4 v0 = *reinterpret_cast<const float4*>(x + (size_t)t * 8);
    float4 v1 = *reinterpret_cast<const float4*>(x + (size_t)t * 8 + 4);
    f16x8 o;
    o[0] = (_Float16)v0.x; o[1] = (_Float16)v0.y; o[2] = (_Float16)v0.z; o[3] = (_Float16)v0.w;
    o[4] = (_Float16)v1.x; o[5] = (_Float16)v1.y; o[6] = (_Float16)v1.z; o[7] = (_Float16)v1.w;
    *reinterpret_cast<f16x8*>(xh + (size_t)t * 8) = o;
  }
}

// ---------------- LDS-tiled coalesced transpose+cast: fw2Th[l][j][k] = fw2[l][k][j] ----
__global__ __launch_bounds__(256) void tr_fw2(const float* __restrict__ fw2,
                                              _Float16* __restrict__ fw2Th) {
  __shared__ _Float16 tile[64][65];
  const int l = blockIdx.z;
  const int k0 = blockIdx.x * 64, j0 = blockIdx.y * 64;
  const size_t base = (size_t)l * 65536;
  const int tid = threadIdx.x;
  for (int idx = tid; idx < 4096; idx += 256) {
    int r = idx >> 6, c = idx & 63;  // r = k-offset, c = j-offset
    tile[r][c] = (_Float16)fw2[base + (size_t)(k0 + r) * 128 + j0 + c];
  }
  __syncthreads();
  for (int idx = tid; idx < 4096; idx += 256) {
    int r = idx >> 6, c = idx & 63;  // r = j-offset, c = k-offset
    fw2Th[base + (size_t)(j0 + r) * 512 + k0 + c] = tile[c][r];
  }
}

// ---------------- pp_bmid: bmid = [bfv0 | bfv0@Wcat + bcat] ----------------
__global__ __launch_bounds__(256) void pp_bmid(const float* __restrict__ bfv,
                                               const float* __restrict__ Wcat,
                                               const float* __restrict__ bcat,
                                               float* __restrict__ bmid) {
  int t = blockIdx.x * 256 + threadIdx.x;
  if (t >= 1024) return;
  if (t < 128) { bmid[t] = bfv[t]; return; }
  int n = t - 128;
  float s0 = bcat[n], s1 = 0.f, s2 = 0.f, s3 = 0.f;
  for (int c = 0; c < 128; c += 4) {
    s0 = fmaf(bfv[c], Wcat[c * 896 + n], s0);
    s1 = fmaf(bfv[c + 1], Wcat[(c + 1) * 896 + n], s1);
    s2 = fmaf(bfv[c + 2], Wcat[(c + 2) * 896 + n], s2);
    s3 = fmaf(bfv[c + 3], Wcat[(c + 3) * 896 + n], s3);
  }
  bmid[t] = ((s0 + s1) + (s2 + s3));
}

// ---------------- Wf[z] = fw1h[z] @ fw2Th[z]^T  (one launch, grid.z=2) -------------
__global__ __launch_bounds__(256) void wf_gemm(const _Float16* __restrict__ fw1h,
                                               const _Float16* __restrict__ fw2Th,
                                               float* __restrict__ Wf,
                                               _Float16* __restrict__ Wfh,
                                               _Float16* __restrict__ BtMid0) {
  const int z = blockIdx.z;
  const _Float16* A = fw1h + z * 65536;
  const _Float16* Bt = fw2Th + z * 65536;
  const int tid = threadIdx.x;
  const int wid = tid >> 6, lane = tid & 63;
  const int wr = wid >> 1, wc = wid & 1;
  const int il = lane & 15, g = lane >> 4;
  const int row0 = wr * 64, col0 = wc * 64;
  const _Float16* Ap = A + (size_t)(row0 + il) * 512 + 8 * g;
  const _Float16* Bp = Bt + (size_t)(col0 + il) * 512 + 8 * g;
  f32x4 acc[4][4];
#pragma unroll
  for (int a = 0; a < 4; ++a)
#pragma unroll
    for (int b = 0; b < 4; ++b) acc[a][b] = (f32x4){0.f, 0.f, 0.f, 0.f};
  for (int k0 = 0; k0 < 512; k0 += 32) {
    f16x8 af[4], bf[4];
#pragma unroll
    for (int f = 0; f < 4; ++f) {
      af[f] = *reinterpret_cast<const f16x8*>(Ap + (size_t)(f * 16) * 512 + k0);
      bf[f] = *reinterpret_cast<const f16x8*>(Bp + (size_t)(f * 16) * 512 + k0);
    }
#pragma unroll
    for (int fi = 0; fi < 4; ++fi)
#pragma unroll
      for (int fj = 0; fj < 4; ++fj)
        acc[fi][fj] = __builtin_amdgcn_mfma_f32_16x16x32_f16(af[fi], bf[fj], acc[fi][fj], 0, 0, 0);
  }
#pragma unroll
  for (int fj = 0; fj < 4; ++fj) {
    const int col = col0 + fj * 16 + il;
#pragma unroll
    for (int fi = 0; fi < 4; ++fi) {
#pragma unroll
      for (int i = 0; i < 4; ++i) {
        const int row = row0 + fi * 16 + g * 4 + i;
        const float v = acc[fi][fj][i];
        Wf[z * 16384 + row * 128 + col] = v;
        if (z == 0) {
          Wfh[row * 128 + col] = (_Float16)v;
          BtMid0[col * 128 + row] = (_Float16)v;
        }
      }
    }
  }
}

// ---------------- MFMA f16 GEMM: C = A[M,K] @ Bt[N,K]^T + bias ----------------
// col-tile on blockIdx.x (fastest) -> A panel L2-resident across consecutive blocks.
// Outputs: Cfh (f16, cols<NF, stride NF), Ch (f16, cols>=choff, stride ldh),
//          ChT (f16 transposed, ChT[col*ldt+row]).
template <bool HAS_CFH, bool HAS_CH, bool HAS_CHT>
__global__ __launch_bounds__(256) void gemm_tn_f16(const _Float16* __restrict__ A,
                                                   const _Float16* __restrict__ Bt,
                                                   const float* __restrict__ bias,
                                                   _Float16* __restrict__ Cfh, int NF,
                                                   _Float16* __restrict__ Ch, int choff, int ldh,
                                                   _Float16* __restrict__ ChT, int ldt,
                                                   int M, int N, int K) {
  const int tid = threadIdx.x;
  const int wid = tid >> 6, lane = tid & 63;
  const int wr = wid >> 1, wc = wid & 1;
  const int il = lane & 15, g = lane >> 4;
  const int row0 = blockIdx.y * 128 + wr * 64;
  const int col0 = blockIdx.x * 128 + wc * 64;
  const _Float16* Ap = A + (size_t)(row0 + il) * K + 8 * g;
  const _Float16* Bp = Bt + (size_t)(col0 + il) * K + 8 * g;
  f32x4 acc[4][4];
#pragma unroll
  for (int a = 0; a < 4; ++a)
#pragma unroll
    for (int b = 0; b < 4; ++b) acc[a][b] = (f32x4){0.f, 0.f, 0.f, 0.f};
  for (int k0 = 0; k0 < K; k0 += 32) {
    f16x8 af[4], bf[4];
#pragma unroll
    for (int f = 0; f < 4; ++f) {
      af[f] = *reinterpret_cast<const f16x8*>(Ap + (size_t)(f * 16) * K + k0);
      bf[f] = *reinterpret_cast<const f16x8*>(Bp + (size_t)(f * 16) * K + k0);
    }
#pragma unroll
    for (int fi = 0; fi < 4; ++fi)
#pragma unroll
      for (int fj = 0; fj < 4; ++fj)
        acc[fi][fj] = __builtin_amdgcn_mfma_f32_16x16x32_f16(af[fi], bf[fj], acc[fi][fj], 0, 0, 0);
  }
#pragma unroll
  for (int fj = 0; fj < 4; ++fj) {
    const int col = col0 + fj * 16 + il;
    const float b = bias[col];
#pragma unroll
    for (int fi = 0; fi < 4; ++fi) {
#pragma unroll
      for (int i = 0; i < 4; ++i) {
        const int row = row0 + fi * 16 + g * 4 + i;
        const float v = acc[fi][fj][i] + b;
        if constexpr (HAS_CFH) { if (col < NF) Cfh[(size_t)row * NF + col] = (_Float16)v; }
        if constexpr (HAS_CH) { if (col >= choff) Ch[(size_t)row * ldh + (col - choff)] = (_Float16)v; }
        if constexpr (HAS_CHT) { ChT[(size_t)col * ldt + row] = (_Float16)v; }
      }
    }
  }
}

// ---------------- fused per-node attention + head-mean + skip + residual + LN -------
// One wave per node (degree-sorted order); 32 lanes per edge, 2 edge slots, prefetch
// depth 2. Lane owns 8 contiguous channels; (lane&31)<16 -> head 0, else head 1.
// Chunk max tracked in registers during QK; exp folded into the V loop.
__global__ __launch_bounds__(256) void node_attn_ln_kernel(
    const _Float16* __restrict__ QKVSh, const _Float16* __restrict__ epth,
    const _Float16* __restrict__ hpre,
    const int* __restrict__ offs, const unsigned* __restrict__ epk,
    const int* __restrict__ order,
    const float* __restrict__ gamma, const float* __restrict__ beta,
    _Float16* __restrict__ hlnh, int Nn) {
  __shared__ float sl0[4][CAP], sl1[4][CAP];
  __shared__ unsigned spk[4][CAP];
  __shared__ float sqe[4][2][10];
  __shared__ __align__(16) _Float16 elds[2560];
  const int tid = threadIdx.x;
  for (int t = tid; t < 1280; t += 256)
    reinterpret_cast<unsigned*>(elds)[t] = reinterpret_cast<const unsigned*>(epth)[t];
  __syncthreads();
  const int w = tid >> 6, lane = tid & 63;
  const int i = order[blockIdx.x * 4 + w];
  const int sub = lane >> 5;     // edge slot 0/1
  const int r = lane & 31;
  const int half = r >> 4;       // head of owned channels
  const int co = r << 3;         // channel offset, 8 ch per lane
  const float scale = 0.08838834764831845f;  // 1/sqrt(128)
  f16x8 qh = *reinterpret_cast<const f16x8*>(QKVSh + (size_t)i * QW + co);
  const f16x2* q2 = reinterpret_cast<const f16x2*>(&qh);
  // prologue: qe[head][ty] = scale * (q_head . e_ty)
#pragma unroll
  for (int ty = 0; ty < 10; ++ty) {
    f16x8 ev = *reinterpret_cast<const f16x8*>(elds + (ty << 8) + co);
    const f16x2* e2 = reinterpret_cast<const f16x2*>(&ev);
    float s = 0.f;
#pragma unroll
    for (int p2 = 0; p2 < 4; ++p2) s = fdot2f(q2[p2], e2[p2], s);
    s += __shfl_xor(s, 1); s += __shfl_xor(s, 2);
    s += __shfl_xor(s, 4); s += __shfl_xor(s, 8);
    if (lane < 32 && (r & 15) == 0) sqe[w][half][ty] = s * scale;
  }
  __threadfence_block();
  float m_me = -1e30f, s_me = 0.f;
  float acc[8] = {0.f};
  const int ebeg = offs[i], eend = offs[i + 1];
  for (int cs = ebeg; cs < eend; cs += CAP) {
    const int cnt = min(CAP, eend - cs);
    const int last = cnt - 1;
    for (int j = lane; j < cnt; j += 64) spk[w][j] = epk[cs + j];
    __threadfence_block();
    // --- QK phase: 2 edges/iter, prefetch depth 2, in-register chunk max ---
    float cmax = -1e30f;
    {
      unsigned pk0 = spk[w][min(sub, last)];
      unsigned pk1 = spk[w][min(2 + sub, last)];
      f16x8 kv0 = *reinterpret_cast<const f16x8*>(QKVSh + (size_t)(pk0 & 0x3FFFF) * QW + 256 + co);
      f16x8 kv1 = *reinterpret_cast<const f16x8*>(QKVSh + (size_t)(pk1 & 0x3FFFF) * QW + 256 + co);
      int ty0 = pk0 >> 18, ty1 = pk1 >> 18;
      for (int j = 0; j < cnt; j += 2) {
        f16x8 kc = kv0;
        const int tyc = ty0;
        kv0 = kv1; ty0 = ty1;
        unsigned pkn = spk[w][min(j + 4 + sub, last)];
        ty1 = pkn >> 18;
        kv1 = *reinterpret_cast<const f16x8*>(QKVSh + (size_t)(pkn & 0x3FFFF) * QW + 256 + co);
        const f16x2* k2 = reinterpret_cast<const f16x2*>(&kc);
        float d = 0.f;
#pragma unroll
        for (int p2 = 0; p2 < 4; ++p2) d = fdot2f(q2[p2], k2[p2], d);
        d += __shfl_xor(d, 1); d += __shfl_xor(d, 2);
        d += __shfl_xor(d, 4); d += __shfl_xor(d, 8);
        d = d * scale + sqe[w][half][tyc];
        if (j + sub < cnt) {
          cmax = fmaxf(cmax, d);
          if ((r & 15) == 0) (half ? sl1 : sl0)[w][j + sub] = d;
        }
      }
    }
    // combine slot maxes (same head at lane^32), rescale running state
    cmax = fmaxf(cmax, __shfl_xor(cmax, 32));
    const float nm = fmaxf(m_me, cmax);
    const float rr = __expf(m_me - nm);
    s_me *= rr;
#pragma unroll
    for (int t = 0; t < 8; ++t) acc[t] *= rr;
    m_me = nm;
    __threadfence_block();
    // --- V phase: 2 edges/iter, prefetch depth 2, exp inline ---
    {
      unsigned pk0 = spk[w][min(sub, last)];
      unsigned pk1 = spk[w][min(2 + sub, last)];
      f16x8 vv0 = *reinterpret_cast<const f16x8*>(QKVSh + (size_t)(pk0 & 0x3FFFF) * QW + 512 + co);
      f16x8 ee0 = *reinterpret_cast<const f16x8*>(elds + ((pk0 >> 18) << 8) + co);
      f16x8 vv1 = *reinterpret_cast<const f16x8*>(QKVSh + (size_t)(pk1 & 0x3FFFF) * QW + 512 + co);
      f16x8 ee1 = *reinterpret_cast<const f16x8*>(elds + ((pk1 >> 18) << 8) + co);
      const float* slme = (half ? sl1 : sl0)[w];
      float ls = 0.f;
      for (int j = 0; j < cnt; j += 2) {
        f16x8 vc = vv0, ec = ee0;
        vv0 = vv1; ee0 = ee1;
        unsigned pkn = spk[w][min(j + 4 + sub, last)];
        vv1 = *reinterpret_cast<const f16x8*>(QKVSh + (size_t)(pkn & 0x3FFFF) * QW + 512 + co);
        ee1 = *reinterpret_cast<const f16x8*>(elds + ((pkn >> 18) << 8) + co);
        const int jc = j + sub;
        float e = 0.f;
        if (jc < cnt) e = __expf(slme[jc] - m_me);
        ls += e;
#pragma unroll
        for (int t = 0; t < 8; ++t) acc[t] = fmaf((float)vc[t] + (float)ec[t], e, acc[t]);
      }
      s_me += ls;
    }
  }
  // combine slots, normalize, head-mean
  const float s_tot = s_me + __shfl_xor(s_me, 32);
  const float invme = 1.f / (s_tot + 1e-16f);
  float g[8];
#pragma unroll
  for (int t = 0; t < 8; ++t) {
    float a = acc[t] + __shfl_xor(acc[t], 32);
    a *= invme;
    g[t] = 0.5f * (a + __shfl_xor(a, 16));
  }
  const int cm = (r & 15) << 3;
  f16x8 sk = *reinterpret_cast<const f16x8*>(QKVSh + (size_t)i * QW + 768 + cm);
  f16x8 pr = *reinterpret_cast<const f16x8*>(hpre + (size_t)i * DD + cm);
  float xv[8];
#pragma unroll
  for (int t = 0; t < 8; ++t) xv[t] = g[t] + (float)sk[t] + (float)pr[t];
  float sm = 0.f;
#pragma unroll
  for (int t = 0; t < 8; ++t) sm += xv[t];
  sm += __shfl_xor(sm, 1); sm += __shfl_xor(sm, 2);
  sm += __shfl_xor(sm, 4); sm += __shfl_xor(sm, 8);
  const float mu = sm * (1.f / 128.f);
  float dx[8], vvs = 0.f;
#pragma unroll
  for (int t = 0; t < 8; ++t) { dx[t] = xv[t] - mu; vvs += dx[t] * dx[t]; }
  vvs += __shfl_xor(vvs, 1); vvs += __shfl_xor(vvs, 2);
  vvs += __shfl_xor(vvs, 4); vvs += __shfl_xor(vvs, 8);
  const float rstd = rsqrtf(vvs * (1.f / 128.f) + 1e-6f);
  if (lane < 16) {
    float4 gm0 = *reinterpret_cast<const float4*>(gamma + cm);
    float4 gm1 = *reinterpret_cast<const float4*>(gamma + cm + 4);
    float4 bt0 = *reinterpret_cast<const float4*>(beta + cm);
    float4 bt1 = *reinterpret_cast<const float4*>(beta + cm + 4);
    f16x8 o;
    o[0] = (_Float16)(dx[0] * rstd * gm0.x + bt0.x);
    o[1] = (_Float16)(dx[1] * rstd * gm0.y + bt0.y);
    o[2] = (_Float16)(dx[2] * rstd * gm0.z + bt0.z);
    o[3] = (_Float16)(dx[3] * rstd * gm0.w + bt0.w);
    o[4] = (_Float16)(dx[4] * rstd * gm1.x + bt1.x);
    o[5] = (_Float16)(dx[5] * rstd * gm1.y + bt1.y);
    o[6] = (_Float16)(dx[6] * rstd * gm1.z + bt1.z);
    o[7] = (_Float16)(dx[7] * rstd * gm1.w + bt1.w);
    *reinterpret_cast<f16x8*>(hlnh + (size_t)i * DD + cm) = o;
  }
}

// ---------------- final: gather mask rows of hln1, apply layer-1 fused FFN ----------------
__global__ __launch_bounds__(128) void final_kernel(const _Float16* __restrict__ hlnh1,
                                                    const float* __restrict__ Wf,
                                                    const float* __restrict__ bfv,
                                                    const int* __restrict__ midx,
                                                    float* __restrict__ out) {
  __shared__ float rowv[128];
  const int b = blockIdx.x, j = threadIdx.x;
  const int row = midx[b];
  rowv[j] = (float)hlnh1[(size_t)row * DD + j];
  __syncthreads();
  const float* w1 = Wf + 16384 + j;  // Wf1[c][j]
  float s = bfv[128 + j];
#pragma unroll 4
  for (int c = 0; c < 128; ++c) s = fmaf(rowv[c], w1[c * 128], s);
  out[b * DD + j] = s;
}

extern "C" void kernel_launch(void* const* d_in, const int* in_sizes, int n_in,
                              void* d_out, int out_size, void* d_ws, size_t ws_size,
                              hipStream_t stream) {
  const float* x    = (const float*)d_in[0];
  const float* hemb = (const float*)d_in[1];
  const float* Wq   = (const float*)d_in[2];
  const float* bq   = (const float*)d_in[3];
  const float* Wk   = (const float*)d_in[4];
  const float* bk   = (const float*)d_in[5];
  const float* Wv   = (const float*)d_in[6];
  const float* bv   = (const float*)d_in[7];
  const float* We   = (const float*)d_in[8];
  const float* Wsk  = (const float*)d_in[9];
  const float* bsk  = (const float*)d_in[10];
  const float* lng  = (const float*)d_in[11];
  const float* lnb  = (const float*)d_in[12];
  const float* fw1  = (const float*)d_in[13];
  const float* fb1  = (const float*)d_in[14];
  const float* fw2  = (const float*)d_in[15];
  const float* fb2  = (const float*)d_in[16];
  const int* eidx   = (const int*)d_in[17];
  const int* etyp   = (const int*)d_in[18];
  const int* midx   = (const int*)d_in[19];

  const int Nn = in_sizes[0] / DD;     // 16000
  const int E = in_sizes[18];          // 256000

  const int* esrc = eidx;
  const int* edst = eidx + E;

  char* p = (char*)d_ws;
  auto alloc = [&](size_t bytes) -> void* {
    void* r = (void*)p;
    p += (bytes + 255) & ~(size_t)255;
    return r;
  };
  _Float16* QKVSh = (_Float16*)alloc((size_t)Nn * QW * 2);
  _Float16* xh    = (_Float16*)alloc((size_t)Nn * DD * 2);
  _Float16* hln0  = (_Float16*)alloc((size_t)Nn * DD * 2);
  _Float16* hln1  = (_Float16*)alloc((size_t)Nn * DD * 2);
  _Float16* h1h   = (_Float16*)alloc((size_t)Nn * DD * 2);
  _Float16* WcatT = (_Float16*)alloc((size_t)QW * DD * 2);
  float*    Wcat  = (float*)alloc((size_t)DD * QW * 4);
  float*    bcat  = (float*)alloc(QW * 4);
  _Float16* epth  = (_Float16*)alloc(2560 * 2);
  _Float16* fw1h  = (_Float16*)alloc((size_t)2 * DD * 512 * 2);
  _Float16* fw2Th = (_Float16*)alloc((size_t)2 * DD * 512 * 2);
  float*    Wf    = (float*)alloc(2 * 128 * 128 * 4);
  _Float16* Wfh   = (_Float16*)alloc(128 * 128 * 2);
  float*    bfv   = (float*)alloc(256 * 4);
  float*    bzero = (float*)alloc(1024 * 4);
  _Float16* BtMid = (_Float16*)alloc((size_t)1024 * 128 * 2);
  float*    bmid  = (float*)alloc(1024 * 4);
  int* counts = (int*)alloc((size_t)Nn * 4);
  int* offs   = (int*)alloc((size_t)(Nn + 1) * 4);
  int* cursor = (int*)alloc((size_t)Nn * 4);
  int* dcur   = (int*)alloc(64 * 4);
  int* order  = (int*)alloc((size_t)Nn * 4);
  unsigned* epk = (unsigned*)alloc((size_t)E * 4);

  // CSR + degree-sorted order (fused)
  hipMemsetAsync(counts, 0, (size_t)Nn * sizeof(int), stream);
  count_kernel<<<(E + 255) / 256, 256, 0, stream>>>(edst, counts, E);
  scan_kernel<<<1, 1024, 0, stream>>>(counts, offs, cursor, dcur, Nn);
  scatter_kernel<<<(E + 255) / 256, 256, 0, stream>>>(edst, esrc, etyp, cursor, epk,
                                                      offs, dcur, order, E, Nn);

  // Precompute
  const int pc_threads = 256 + 2560 + 114688 + 896 + 1024 + 16384 + Nn * 16;
  pp_cast<<<(pc_threads + 255) / 256, 256, 0, stream>>>(
      Wq, Wk, Wv, Wsk, bq, bk, bv, bsk, hemb, We, x, fw1, fb1, fw2, fb2,
      WcatT, Wcat, bcat, epth, xh, fw1h, bfv, bzero, Nn);
  tr_fw2<<<dim3(8, 2, 2), 256, 0, stream>>>(fw2, fw2Th);
  pp_bmid<<<4, 256, 0, stream>>>(bfv, Wcat, bcat, bmid);
  wf_gemm<<<dim3(1, 1, 2), 256, 0, stream>>>(fw1h, fw2Th, Wf, Wfh, BtMid);
  // BtMid[128:1024] = (Wf0 @ Wcat)^T
  gemm_tn_f16<false, false, true><<<dim3(7, 1), 256, 0, stream>>>(
      Wfh, WcatT, bzero, nullptr, 0, nullptr, 0, 0, BtMid + 16384, 128, 128, 896, 128);

  // Layer 0: QKVS0 = xh @ Wcat + bcat
  gemm_tn_f16<false, true, false><<<dim3(QW / 128, Nn / 128), 256, 0, stream>>>(
      xh, WcatT, bcat, nullptr, 0, QKVSh, 0, QW, nullptr, 0, Nn, QW, DD);
  node_attn_ln_kernel<<<Nn / 4, 256, 0, stream>>>(QKVSh, epth, xh, offs, epk, order,
                                                  lng, lnb, hln0, Nn);
  // Fused: [h1h (f16) | QKVS1 (f16)] = hln0 @ [Wf0 | Wf0@Wcat] + bmid
  gemm_tn_f16<true, true, false><<<dim3(1024 / 128, Nn / 128), 256, 0, stream>>>(
      hln0, BtMid, bmid, h1h, 128, QKVSh, 128, QW, nullptr, 0, Nn, 1024, DD);
  node_attn_ln_kernel<<<Nn / 4, 256, 0, stream>>>(QKVSh, epth, h1h, offs, epk, order,
                                                  lng + DD, lnb + DD, hln1, Nn);
  final_kernel<<<64, 128, 0, stream>>>(hln1, Wf, bfv, midx, (float*)d_out);
}

// Round 8
// 257.375 us; speedup vs baseline: 1.5091x; 1.2401x over previous
//
#include <hip/hip_runtime.h>
#include <hip/hip_bf16.h>
#include <math.h>

#define DD 128
#define QW 896       // 256(Q)+256(K)+256(V)+128(skip)
#define CAP 128
#define NB 125       // coarse buckets (dst>>7), 128 nodes each
#define BCAP 4096    // max edges per coarse bucket (mean 2048, sigma~45)

typedef _Float16 f16x8 __attribute__((ext_vector_type(8)));
typedef _Float16 f16x2 __attribute__((ext_vector_type(2)));
typedef float f32x4 __attribute__((ext_vector_type(4)));

__device__ __forceinline__ float fdot2f(f16x2 a, f16x2 b, float c) {
#if __has_builtin(__builtin_amdgcn_fdot2)
  return __builtin_amdgcn_fdot2(a, b, c, false);
#else
  return fmaf((float)a[0], (float)b[0], fmaf((float)a[1], (float)b[1], c));
#endif
}

// ---------------- CSR build: two-level LDS counting sort ----------------
// pass 1a: coarse bucket counts (LDS pre-aggregated)
__global__ __launch_bounds__(256) void csr_count(const int* __restrict__ edst,
                                                 int* __restrict__ bcnt, int E) {
  __shared__ int h[NB];
  const int tid = threadIdx.x;
  if (tid < NB) h[tid] = 0;
  __syncthreads();
  const int e0 = blockIdx.x * 2048;
  for (int k = 0; k < 8; ++k) {
    int e = e0 + k * 256 + tid;
    if (e < E) atomicAdd(&h[edst[e] >> 7], 1);
  }
  __syncthreads();
  if (tid < NB && h[tid]) atomicAdd(&bcnt[tid], h[tid]);
}

// pass 1b: scan bucket counts -> bases/cursors; also offs[Nn]=E
__global__ __launch_bounds__(128) void csr_scan(const int* __restrict__ bcnt,
                                                int* __restrict__ bbase,
                                                int* __restrict__ bcursor,
                                                int* __restrict__ offs, int E, int Nn) {
  __shared__ int sc[128];
  const int tid = threadIdx.x;
  sc[tid] = (tid < NB) ? bcnt[tid] : 0;
  __syncthreads();
  for (int d = 1; d < 128; d <<= 1) {
    int t = (tid >= d) ? sc[tid - d] : 0;
    __syncthreads();
    sc[tid] += t;
    __syncthreads();
  }
  const int excl = tid ? sc[tid - 1] : 0;
  if (tid < NB) { bbase[tid] = excl; bcursor[tid] = excl; }
  if (tid == 0) { bbase[NB] = E; offs[Nn] = E; }
}

// pass 1c: scatter packed edges into coarse buckets (block-reserved runs)
__global__ __launch_bounds__(256) void csr_scatter(const int* __restrict__ edst,
                                                   const int* __restrict__ esrc,
                                                   const int* __restrict__ etyp,
                                                   int* __restrict__ bcursor,
                                                   unsigned* __restrict__ ebuf, int E) {
  __shared__ int h[NB], cur[NB];
  const int tid = threadIdx.x;
  if (tid < NB) h[tid] = 0;
  __syncthreads();
  const int e0 = blockIdx.x * 2048;
  int dd[8];
  for (int k = 0; k < 8; ++k) {
    int e = e0 + k * 256 + tid;
    dd[k] = (e < E) ? edst[e] : -1;
    if (dd[k] >= 0) atomicAdd(&h[dd[k] >> 7], 1);
  }
  __syncthreads();
  if (tid < NB && h[tid]) cur[tid] = atomicAdd(&bcursor[tid], h[tid]);
  __syncthreads();
  for (int k = 0; k < 8; ++k) {
    int e = e0 + k * 256 + tid;
    if (dd[k] >= 0) {
      int pos = atomicAdd(&cur[dd[k] >> 7], 1);
      ebuf[pos] = (unsigned)esrc[e] | ((unsigned)etyp[e] << 14) |
                  ((unsigned)(dd[k] & 127) << 18);
    }
  }
}

// pass 2: per-bucket fine sort in LDS -> offs, epk (coalesced), degree histogram
__global__ __launch_bounds__(256) void csr_fine(const unsigned* __restrict__ ebuf,
                                                const int* __restrict__ bbase,
                                                unsigned* __restrict__ epk,
                                                int* __restrict__ offs,
                                                int* __restrict__ dcnt) {
  __shared__ unsigned sed[BCAP];
  __shared__ unsigned sout[BCAP];
  __shared__ int fh[128], sc[128], fc[128], hb[64];
  const int b = blockIdx.x, tid = threadIdx.x;
  const int base = bbase[b], cnt = bbase[b + 1] - base;
  for (int idx = tid; idx < cnt; idx += 256) sed[idx] = ebuf[base + idx];
  if (tid < 128) fh[tid] = 0;
  if (tid < 64) hb[tid] = 0;
  __syncthreads();
  for (int idx = tid; idx < cnt; idx += 256) atomicAdd(&fh[(sed[idx] >> 18) & 127], 1);
  __syncthreads();
  if (tid < 128) sc[tid] = fh[tid];
  __syncthreads();
  for (int d = 1; d < 128; d <<= 1) {
    int t = (tid < 128 && tid >= d) ? sc[tid - d] : 0;
    __syncthreads();
    if (tid < 128) sc[tid] += t;
    __syncthreads();
  }
  if (tid < 128) {
    const int excl = tid ? sc[tid - 1] : 0;
    offs[b * 128 + tid] = base + excl;
    fc[tid] = excl;
    atomicAdd(&hb[min(fh[tid], 63)], 1);
  }
  __syncthreads();
  if (tid < 64 && hb[tid]) atomicAdd(&dcnt[tid], hb[tid]);
  for (int idx = tid; idx < cnt; idx += 256) {
    const unsigned v = sed[idx];
    const int pos = atomicAdd(&fc[(v >> 18) & 127], 1);
    sout[pos] = (v & 0x3FFF) | (((v >> 14) & 0xF) << 18);  // src | typ<<18
  }
  __syncthreads();
  for (int idx = tid; idx < cnt; idx += 256) epk[base + idx] = sout[idx];
}

// descending-degree bucket cursors
__global__ __launch_bounds__(64) void deg_scan(const int* __restrict__ dcnt,
                                               int* __restrict__ dcur) {
  const int t = threadIdx.x;
  int s = 0;
  for (int d = t + 1; d < 64; ++d) s += dcnt[d];
  dcur[t] = s;
}

// degree-sorted node order (LDS-aggregated atomics)
__global__ __launch_bounds__(256) void deg_order(const int* __restrict__ offs,
                                                 int* __restrict__ dcur,
                                                 int* __restrict__ order, int Nn) {
  __shared__ int h[64], cbase[64];
  const int tid = threadIdx.x;
  const int i = blockIdx.x * 256 + tid;
  if (tid < 64) h[tid] = 0;
  __syncthreads();
  int bk = -1;
  if (i < Nn) {
    bk = min(offs[i + 1] - offs[i], 63);
    atomicAdd(&h[bk], 1);
  }
  __syncthreads();
  if (tid < 64) {
    const int c = h[tid];
    cbase[tid] = c ? atomicAdd(&dcur[tid], c) : 0;
    h[tid] = 0;
  }
  __syncthreads();
  if (bk >= 0) {
    const int pos = cbase[bk] + atomicAdd(&h[bk], 1);
    order[pos] = i;
  }
}

// ---------------- pp_cast: all parallel precompute ----------------
__global__ __launch_bounds__(256) void pp_cast(
    const float* __restrict__ Wq, const float* __restrict__ Wk,
    const float* __restrict__ Wv, const float* __restrict__ Wsk,
    const float* __restrict__ bq, const float* __restrict__ bk,
    const float* __restrict__ bv, const float* __restrict__ bsk,
    const float* __restrict__ hemb, const float* __restrict__ We,
    const float* __restrict__ x,
    const float* __restrict__ fw1, const float* __restrict__ fb1,
    const float* __restrict__ fw2, const float* __restrict__ fb2,
    _Float16* __restrict__ WcatT, float* __restrict__ Wcat, float* __restrict__ bcat,
    _Float16* __restrict__ epth, _Float16* __restrict__ xh,
    _Float16* __restrict__ fw1h,
    float* __restrict__ bfv, float* __restrict__ bzero, int Nn) {
  int t = blockIdx.x * 256 + threadIdx.x;
  if (t < 256) {  // bfv[l][j]: 512-dot, 4 accumulators
    int l = t >> 7, j = t & 127;
    const float* b1 = fb1 + l * 512;
    const float* w2 = fw2 + (size_t)l * 65536 + j;
    float s0 = fb2[l * 128 + j], s1 = 0.f, s2 = 0.f, s3 = 0.f;
    for (int k = 0; k < 512; k += 4) {
      s0 = fmaf(b1[k], w2[(size_t)k * 128], s0);
      s1 = fmaf(b1[k + 1], w2[(size_t)(k + 1) * 128], s1);
      s2 = fmaf(b1[k + 2], w2[(size_t)(k + 2) * 128], s2);
      s3 = fmaf(b1[k + 3], w2[(size_t)(k + 3) * 128], s3);
    }
    bfv[t] = ((s0 + s1) + (s2 + s3));
    return;
  }
  t -= 256;
  if (t < 2560) {  // eproj
    int ty = t >> 8, col = t & 255;
    float s0 = 0.f, s1 = 0.f, s2 = 0.f, s3 = 0.f;
    const float* hr = hemb + ty * 128;
    for (int c = 0; c < 128; c += 4) {
      s0 = fmaf(hr[c], We[c * 256 + col], s0);
      s1 = fmaf(hr[c + 1], We[(c + 1) * 256 + col], s1);
      s2 = fmaf(hr[c + 2], We[(c + 2) * 256 + col], s2);
      s3 = fmaf(hr[c + 3], We[(c + 3) * 256 + col], s3);
    }
    epth[t] = (_Float16)((s0 + s1) + (s2 + s3));
    return;
  }
  t -= 2560;
  if (t < 114688) {  // WcatT f16 [896][128] + Wcat f32 [128][896]
    int n = t >> 7, k = t & 127;
    float v;
    if (n < 256) v = Wq[k * 256 + n];
    else if (n < 512) v = Wk[k * 256 + (n - 256)];
    else if (n < 768) v = Wv[k * 256 + (n - 512)];
    else v = Wsk[k * 128 + (n - 768)];
    WcatT[t] = (_Float16)v;
    Wcat[k * 896 + n] = v;
    return;
  }
  t -= 114688;
  if (t < 896) {
    float v;
    if (t < 256) v = bq[t];
    else if (t < 512) v = bk[t - 256];
    else if (t < 768) v = bv[t - 512];
    else v = bsk[t - 768];
    bcat[t] = v;
    return;
  }
  t -= 896;
  if (t < 1024) { bzero[t] = 0.f; return; }
  t -= 1024;
  if (t < 16384) {  // fw1 cast, 8/thread
    float4 v0 = *reinterpret_cast<const float4*>(fw1 + (size_t)t * 8);
    float4 v1 = *reinterpret_cast<const float4*>(fw1 + (size_t)t * 8 + 4);
    f16x8 o;
    o[0] = (_Float16)v0.x; o[1] = (_Float16)v0.y; o[2] = (_Float16)v0.z; o[3] = (_Float16)v0.w;
    o[4] = (_Float16)v1.x; o[5] = (_Float16)v1.y; o[6] = (_Float16)v1.z; o[7] = (_Float16)v1.w;
    *reinterpret_cast<f16x8*>(fw1h + (size_t)t * 8) = o;
    return;
  }
  t -= 16384;
  if (t < Nn * 16) {  // cast x -> f16, 8/thread
    float4 v0 = *reinterpret_cast<const float4*>(x + (size_t)t * 8);
    float4 v1 = *reinterpret_cast<const float4*>(x + (size_t)t * 8 + 4);
    f16x8 o;
    o[0] = (_Float16)v0.x; o[1] = (_Float16)v0.y; o[2] = (_Float16)v0.z; o[3] = (_Float16)v0.w;
    o[4] = (_Float16)v1.x; o[5] = (_Float16)v1.y; o[6] = (_Float16)v1.z; o[7] = (_Float16)v1.w;
    *reinterpret_cast<f16x8*>(xh + (size_t)t * 8) = o;
  }
}

// ---------------- LDS-tiled coalesced transpose+cast: fw2Th[l][j][k] = fw2[l][k][j] ----
__global__ __launch_bounds__(256) void tr_fw2(const float* __restrict__ fw2,
                                              _Float16* __restrict__ fw2Th) {
  __shared__ _Float16 tile[64][65];
  const int l = blockIdx.z;
  const int k0 = blockIdx.x * 64, j0 = blockIdx.y * 64;
  const size_t base = (size_t)l * 65536;
  const int tid = threadIdx.x;
  for (int idx = tid; idx < 4096; idx += 256) {
    int r = idx >> 6, c = idx & 63;
    tile[r][c] = (_Float16)fw2[base + (size_t)(k0 + r) * 128 + j0 + c];
  }
  __syncthreads();
  for (int idx = tid; idx < 4096; idx += 256) {
    int r = idx >> 6, c = idx & 63;
    fw2Th[base + (size_t)(j0 + r) * 512 + k0 + c] = tile[c][r];
  }
}

// ---------------- pp_bmid: bmid = [bfv0 | bfv0@Wcat + bcat] ----------------
__global__ __launch_bounds__(256) void pp_bmid(const float* __restrict__ bfv,
                                               const float* __restrict__ Wcat,
                                               const float* __restrict__ bcat,
                                               float* __restrict__ bmid) {
  int t = blockIdx.x * 256 + threadIdx.x;
  if (t >= 1024) return;
  if (t < 128) { bmid[t] = bfv[t]; return; }
  int n = t - 128;
  float s0 = bcat[n], s1 = 0.f, s2 = 0.f, s3 = 0.f;
  for (int c = 0; c < 128; c += 4) {
    s0 = fmaf(bfv[c], Wcat[c * 896 + n], s0);
    s1 = fmaf(bfv[c + 1], Wcat[(c + 1) * 896 + n], s1);
    s2 = fmaf(bfv[c + 2], Wcat[(c + 2) * 896 + n], s2);
    s3 = fmaf(bfv[c + 3], Wcat[(c + 3) * 896 + n], s3);
  }
  bmid[t] = ((s0 + s1) + (s2 + s3));
}

// ---------------- Wf[z] = fw1h[z] @ fw2Th[z]^T  (one launch, grid.z=2) -------------
__global__ __launch_bounds__(256) void wf_gemm(const _Float16* __restrict__ fw1h,
                                               const _Float16* __restrict__ fw2Th,
                                               float* __restrict__ Wf,
                                               _Float16* __restrict__ Wfh,
                                               _Float16* __restrict__ BtMid0) {
  const int z = blockIdx.z;
  const _Float16* A = fw1h + z * 65536;
  const _Float16* Bt = fw2Th + z * 65536;
  const int tid = threadIdx.x;
  const int wid = tid >> 6, lane = tid & 63;
  const int wr = wid >> 1, wc = wid & 1;
  const int il = lane & 15, g = lane >> 4;
  const int row0 = wr * 64, col0 = wc * 64;
  const _Float16* Ap = A + (size_t)(row0 + il) * 512 + 8 * g;
  const _Float16* Bp = Bt + (size_t)(col0 + il) * 512 + 8 * g;
  f32x4 acc[4][4];
#pragma unroll
  for (int a = 0; a < 4; ++a)
#pragma unroll
    for (int b = 0; b < 4; ++b) acc[a][b] = (f32x4){0.f, 0.f, 0.f, 0.f};
  for (int k0 = 0; k0 < 512; k0 += 32) {
    f16x8 af[4], bf[4];
#pragma unroll
    for (int f = 0; f < 4; ++f) {
      af[f] = *reinterpret_cast<const f16x8*>(Ap + (size_t)(f * 16) * 512 + k0);
      bf[f] = *reinterpret_cast<const f16x8*>(Bp + (size_t)(f * 16) * 512 + k0);
    }
#pragma unroll
    for (int fi = 0; fi < 4; ++fi)
#pragma unroll
      for (int fj = 0; fj < 4; ++fj)
        acc[fi][fj] = __builtin_amdgcn_mfma_f32_16x16x32_f16(af[fi], bf[fj], acc[fi][fj], 0, 0, 0);
  }
#pragma unroll
  for (int fj = 0; fj < 4; ++fj) {
    const int col = col0 + fj * 16 + il;
#pragma unroll
    for (int fi = 0; fi < 4; ++fi) {
#pragma unroll
      for (int i = 0; i < 4; ++i) {
        const int row = row0 + fi * 16 + g * 4 + i;
        const float v = acc[fi][fj][i];
        Wf[z * 16384 + row * 128 + col] = v;
        if (z == 0) {
          Wfh[row * 128 + col] = (_Float16)v;
          BtMid0[col * 128 + row] = (_Float16)v;
        }
      }
    }
  }
}

// ---------------- MFMA f16 GEMM: C = A[M,K] @ Bt[N,K]^T + bias ----------------
// col-tile on blockIdx.x (fastest) -> A panel L2-resident across consecutive blocks.
template <bool HAS_CFH, bool HAS_CH, bool HAS_CHT>
__global__ __launch_bounds__(256) void gemm_tn_f16(const _Float16* __restrict__ A,
                                                   const _Float16* __restrict__ Bt,
                                                   const float* __restrict__ bias,
                                                   _Float16* __restrict__ Cfh, int NF,
                                                   _Float16* __restrict__ Ch, int choff, int ldh,
                                                   _Float16* __restrict__ ChT, int ldt,
                                                   int M, int N, int K) {
  const int tid = threadIdx.x;
  const int wid = tid >> 6, lane = tid & 63;
  const int wr = wid >> 1, wc = wid & 1;
  const int il = lane & 15, g = lane >> 4;
  const int row0 = blockIdx.y * 128 + wr * 64;
  const int col0 = blockIdx.x * 128 + wc * 64;
  const _Float16* Ap = A + (size_t)(row0 + il) * K + 8 * g;
  const _Float16* Bp = Bt + (size_t)(col0 + il) * K + 8 * g;
  f32x4 acc[4][4];
#pragma unroll
  for (int a = 0; a < 4; ++a)
#pragma unroll
    for (int b = 0; b < 4; ++b) acc[a][b] = (f32x4){0.f, 0.f, 0.f, 0.f};
  for (int k0 = 0; k0 < K; k0 += 32) {
    f16x8 af[4], bf[4];
#pragma unroll
    for (int f = 0; f < 4; ++f) {
      af[f] = *reinterpret_cast<const f16x8*>(Ap + (size_t)(f * 16) * K + k0);
      bf[f] = *reinterpret_cast<const f16x8*>(Bp + (size_t)(f * 16) * K + k0);
    }
#pragma unroll
    for (int fi = 0; fi < 4; ++fi)
#pragma unroll
      for (int fj = 0; fj < 4; ++fj)
        acc[fi][fj] = __builtin_amdgcn_mfma_f32_16x16x32_f16(af[fi], bf[fj], acc[fi][fj], 0, 0, 0);
  }
#pragma unroll
  for (int fj = 0; fj < 4; ++fj) {
    const int col = col0 + fj * 16 + il;
    const float b = bias[col];
#pragma unroll
    for (int fi = 0; fi < 4; ++fi) {
#pragma unroll
      for (int i = 0; i < 4; ++i) {
        const int row = row0 + fi * 16 + g * 4 + i;
        const float v = acc[fi][fj][i] + b;
        if constexpr (HAS_CFH) { if (col < NF) Cfh[(size_t)row * NF + col] = (_Float16)v; }
        if constexpr (HAS_CH) { if (col >= choff) Ch[(size_t)row * ldh + (col - choff)] = (_Float16)v; }
        if constexpr (HAS_CHT) { ChT[(size_t)col * ldt + row] = (_Float16)v; }
      }
    }
  }
}

// ---------------- fused per-node attention + head-mean + skip + residual + LN -------
__global__ __launch_bounds__(256) void node_attn_ln_kernel(
    const _Float16* __restrict__ QKVSh, const _Float16* __restrict__ epth,
    const _Float16* __restrict__ hpre,
    const int* __restrict__ offs, const unsigned* __restrict__ epk,
    const int* __restrict__ order,
    const float* __restrict__ gamma, const float* __restrict__ beta,
    _Float16* __restrict__ hlnh, int Nn) {
  __shared__ float sl0[4][CAP], sl1[4][CAP];
  __shared__ unsigned spk[4][CAP];
  __shared__ float sqe[4][2][10];
  __shared__ __align__(16) _Float16 elds[2560];
  const int tid = threadIdx.x;
  for (int t = tid; t < 1280; t += 256)
    reinterpret_cast<unsigned*>(elds)[t] = reinterpret_cast<const unsigned*>(epth)[t];
  __syncthreads();
  const int w = tid >> 6, lane = tid & 63;
  const int i = order[blockIdx.x * 4 + w];
  const int sub = lane >> 5;
  const int r = lane & 31;
  const int half = r >> 4;
  const int co = r << 3;
  const float scale = 0.08838834764831845f;  // 1/sqrt(128)
  f16x8 qh = *reinterpret_cast<const f16x8*>(QKVSh + (size_t)i * QW + co);
  const f16x2* q2 = reinterpret_cast<const f16x2*>(&qh);
#pragma unroll
  for (int ty = 0; ty < 10; ++ty) {
    f16x8 ev = *reinterpret_cast<const f16x8*>(elds + (ty << 8) + co);
    const f16x2* e2 = reinterpret_cast<const f16x2*>(&ev);
    float s = 0.f;
#pragma unroll
    for (int p2 = 0; p2 < 4; ++p2) s = fdot2f(q2[p2], e2[p2], s);
    s += __shfl_xor(s, 1); s += __shfl_xor(s, 2);
    s += __shfl_xor(s, 4); s += __shfl_xor(s, 8);
    if (lane < 32 && (r & 15) == 0) sqe[w][half][ty] = s * scale;
  }
  __threadfence_block();
  float m_me = -1e30f, s_me = 0.f;
  float acc[8] = {0.f};
  const int ebeg = offs[i], eend = offs[i + 1];
  for (int cs = ebeg; cs < eend; cs += CAP) {
    const int cnt = min(CAP, eend - cs);
    const int last = cnt - 1;
    for (int j = lane; j < cnt; j += 64) spk[w][j] = epk[cs + j];
    __threadfence_block();
    float cmax = -1e30f;
    {
      unsigned pk0 = spk[w][min(sub, last)];
      unsigned pk1 = spk[w][min(2 + sub, last)];
      f16x8 kv0 = *reinterpret_cast<const f16x8*>(QKVSh + (size_t)(pk0 & 0x3FFFF) * QW + 256 + co);
      f16x8 kv1 = *reinterpret_cast<const f16x8*>(QKVSh + (size_t)(pk1 & 0x3FFFF) * QW + 256 + co);
      int ty0 = pk0 >> 18, ty1 = pk1 >> 18;
      for (int j = 0; j < cnt; j += 2) {
        f16x8 kc = kv0;
        const int tyc = ty0;
        kv0 = kv1; ty0 = ty1;
        unsigned pkn = spk[w][min(j + 4 + sub, last)];
        ty1 = pkn >> 18;
        kv1 = *reinterpret_cast<const f16x8*>(QKVSh + (size_t)(pkn & 0x3FFFF) * QW + 256 + co);
        const f16x2* k2 = reinterpret_cast<const f16x2*>(&kc);
        float d = 0.f;
#pragma unroll
        for (int p2 = 0; p2 < 4; ++p2) d = fdot2f(q2[p2], k2[p2], d);
        d += __shfl_xor(d, 1); d += __shfl_xor(d, 2);
        d += __shfl_xor(d, 4); d += __shfl_xor(d, 8);
        d = d * scale + sqe[w][half][tyc];
        if (j + sub < cnt) {
          cmax = fmaxf(cmax, d);
          if ((r & 15) == 0) (half ? sl1 : sl0)[w][j + sub] = d;
        }
      }
    }
    cmax = fmaxf(cmax, __shfl_xor(cmax, 32));
    const float nm = fmaxf(m_me, cmax);
    const float rr = __expf(m_me - nm);
    s_me *= rr;
#pragma unroll
    for (int t = 0; t < 8; ++t) acc[t] *= rr;
    m_me = nm;
    __threadfence_block();
    {
      unsigned pk0 = spk[w][min(sub, last)];
      unsigned pk1 = spk[w][min(2 + sub, last)];
      f16x8 vv0 = *reinterpret_cast<const f16x8*>(QKVSh + (size_t)(pk0 & 0x3FFFF) * QW + 512 + co);
      f16x8 ee0 = *reinterpret_cast<const f16x8*>(elds + ((pk0 >> 18) << 8) + co);
      f16x8 vv1 = *reinterpret_cast<const f16x8*>(QKVSh + (size_t)(pk1 & 0x3FFFF) * QW + 512 + co);
      f16x8 ee1 = *reinterpret_cast<const f16x8*>(elds + ((pk1 >> 18) << 8) + co);
      const float* slme = (half ? sl1 : sl0)[w];
      float ls = 0.f;
      for (int j = 0; j < cnt; j += 2) {
        f16x8 vc = vv0, ec = ee0;
        vv0 = vv1; ee0 = ee1;
        unsigned pkn = spk[w][min(j + 4 + sub, last)];
        vv1 = *reinterpret_cast<const f16x8*>(QKVSh + (size_t)(pkn & 0x3FFFF) * QW + 512 + co);
        ee1 = *reinterpret_cast<const f16x8*>(elds + ((pkn >> 18) << 8) + co);
        const int jc = j + sub;
        float e = 0.f;
        if (jc < cnt) e = __expf(slme[jc] - m_me);
        ls += e;
#pragma unroll
        for (int t = 0; t < 8; ++t) acc[t] = fmaf((float)vc[t] + (float)ec[t], e, acc[t]);
      }
      s_me += ls;
    }
  }
  const float s_tot = s_me + __shfl_xor(s_me, 32);
  const float invme = 1.f / (s_tot + 1e-16f);
  float g[8];
#pragma unroll
  for (int t = 0; t < 8; ++t) {
    float a = acc[t] + __shfl_xor(acc[t], 32);
    a *= invme;
    g[t] = 0.5f * (a + __shfl_xor(a, 16));
  }
  const int cm = (r & 15) << 3;
  f16x8 sk = *reinterpret_cast<const f16x8*>(QKVSh + (size_t)i * QW + 768 + cm);
  f16x8 pr = *reinterpret_cast<const f16x8*>(hpre + (size_t)i * DD + cm);
  float xv[8];
#pragma unroll
  for (int t = 0; t < 8; ++t) xv[t] = g[t] + (float)sk[t] + (float)pr[t];
  float sm = 0.f;
#pragma unroll
  for (int t = 0; t < 8; ++t) sm += xv[t];
  sm += __shfl_xor(sm, 1); sm += __shfl_xor(sm, 2);
  sm += __shfl_xor(sm, 4); sm += __shfl_xor(sm, 8);
  const float mu = sm * (1.f / 128.f);
  float dx[8], vvs = 0.f;
#pragma unroll
  for (int t = 0; t < 8; ++t) { dx[t] = xv[t] - mu; vvs += dx[t] * dx[t]; }
  vvs += __shfl_xor(vvs, 1); vvs += __shfl_xor(vvs, 2);
  vvs += __shfl_xor(vvs, 4); vvs += __shfl_xor(vvs, 8);
  const float rstd = rsqrtf(vvs * (1.f / 128.f) + 1e-6f);
  if (lane < 16) {
    float4 gm0 = *reinterpret_cast<const float4*>(gamma + cm);
    float4 gm1 = *reinterpret_cast<const float4*>(gamma + cm + 4);
    float4 bt0 = *reinterpret_cast<const float4*>(beta + cm);
    float4 bt1 = *reinterpret_cast<const float4*>(beta + cm + 4);
    f16x8 o;
    o[0] = (_Float16)(dx[0] * rstd * gm0.x + bt0.x);
    o[1] = (_Float16)(dx[1] * rstd * gm0.y + bt0.y);
    o[2] = (_Float16)(dx[2] * rstd * gm0.z + bt0.z);
    o[3] = (_Float16)(dx[3] * rstd * gm0.w + bt0.w);
    o[4] = (_Float16)(dx[4] * rstd * gm1.x + bt1.x);
    o[5] = (_Float16)(dx[5] * rstd * gm1.y + bt1.y);
    o[6] = (_Float16)(dx[6] * rstd * gm1.z + bt1.z);
    o[7] = (_Float16)(dx[7] * rstd * gm1.w + bt1.w);
    *reinterpret_cast<f16x8*>(hlnh + (size_t)i * DD + cm) = o;
  }
}

// ---------------- final: gather mask rows of hln1, apply layer-1 fused FFN ----------------
__global__ __launch_bounds__(128) void final_kernel(const _Float16* __restrict__ hlnh1,
                                                    const float* __restrict__ Wf,
                                                    const float* __restrict__ bfv,
                                                    const int* __restrict__ midx,
                                                    float* __restrict__ out) {
  __shared__ float rowv[128];
  const int b = blockIdx.x, j = threadIdx.x;
  const int row = midx[b];
  rowv[j] = (float)hlnh1[(size_t)row * DD + j];
  __syncthreads();
  const float* w1 = Wf + 16384 + j;
  float s = bfv[128 + j];
#pragma unroll 4
  for (int c = 0; c < 128; ++c) s = fmaf(rowv[c], w1[c * 128], s);
  out[b * DD + j] = s;
}

extern "C" void kernel_launch(void* const* d_in, const int* in_sizes, int n_in,
                              void* d_out, int out_size, void* d_ws, size_t ws_size,
                              hipStream_t stream) {
  const float* x    = (const float*)d_in[0];
  const float* hemb = (const float*)d_in[1];
  const float* Wq   = (const float*)d_in[2];
  const float* bq   = (const float*)d_in[3];
  const float* Wk   = (const float*)d_in[4];
  const float* bk   = (const float*)d_in[5];
  const float* Wv   = (const float*)d_in[6];
  const float* bv   = (const float*)d_in[7];
  const float* We   = (const float*)d_in[8];
  const float* Wsk  = (const float*)d_in[9];
  const float* bsk  = (const float*)d_in[10];
  const float* lng  = (const float*)d_in[11];
  const float* lnb  = (const float*)d_in[12];
  const float* fw1  = (const float*)d_in[13];
  const float* fb1  = (const float*)d_in[14];
  const float* fw2  = (const float*)d_in[15];
  const float* fb2  = (const float*)d_in[16];
  const int* eidx   = (const int*)d_in[17];
  const int* etyp   = (const int*)d_in[18];
  const int* midx   = (const int*)d_in[19];

  const int Nn = in_sizes[0] / DD;     // 16000
  const int E = in_sizes[18];          // 256000

  const int* esrc = eidx;
  const int* edst = eidx + E;

  char* p = (char*)d_ws;
  auto alloc = [&](size_t bytes) -> void* {
    void* r = (void*)p;
    p += (bytes + 255) & ~(size_t)255;
    return r;
  };
  _Float16* QKVSh = (_Float16*)alloc((size_t)Nn * QW * 2);
  _Float16* xh    = (_Float16*)alloc((size_t)Nn * DD * 2);
  _Float16* hln0  = (_Float16*)alloc((size_t)Nn * DD * 2);
  _Float16* hln1  = (_Float16*)alloc((size_t)Nn * DD * 2);
  _Float16* h1h   = (_Float16*)alloc((size_t)Nn * DD * 2);
  _Float16* WcatT = (_Float16*)alloc((size_t)QW * DD * 2);
  float*    Wcat  = (float*)alloc((size_t)DD * QW * 4);
  float*    bcat  = (float*)alloc(QW * 4);
  _Float16* epth  = (_Float16*)alloc(2560 * 2);
  _Float16* fw1h  = (_Float16*)alloc((size_t)2 * DD * 512 * 2);
  _Float16* fw2Th = (_Float16*)alloc((size_t)2 * DD * 512 * 2);
  float*    Wf    = (float*)alloc(2 * 128 * 128 * 4);
  _Float16* Wfh   = (_Float16*)alloc(128 * 128 * 2);
  float*    bfv   = (float*)alloc(256 * 4);
  float*    bzero = (float*)alloc(1024 * 4);
  _Float16* BtMid = (_Float16*)alloc((size_t)1024 * 128 * 2);
  float*    bmid  = (float*)alloc(1024 * 4);
  int* offs   = (int*)alloc((size_t)(Nn + 1) * 4);
  int* bcnt   = (int*)alloc((NB + 1) * 4);
  int* bbase  = (int*)alloc((NB + 1) * 4);
  int* bcursor= (int*)alloc((NB + 1) * 4);
  int* dcnt   = (int*)alloc(64 * 4);
  int* dcur   = (int*)alloc(64 * 4);
  int* order  = (int*)alloc((size_t)Nn * 4);
  unsigned* ebuf = (unsigned*)alloc((size_t)E * 4);
  unsigned* epk  = (unsigned*)alloc((size_t)E * 4);

  // CSR build: two-level LDS counting sort
  hipMemsetAsync(bcnt, 0, (NB + 1) * sizeof(int), stream);
  hipMemsetAsync(dcnt, 0, 64 * sizeof(int), stream);
  csr_count<<<(E + 2047) / 2048, 256, 0, stream>>>(edst, bcnt, E);
  csr_scan<<<1, 128, 0, stream>>>(bcnt, bbase, bcursor, offs, E, Nn);
  csr_scatter<<<(E + 2047) / 2048, 256, 0, stream>>>(edst, esrc, etyp, bcursor, ebuf, E);
  csr_fine<<<NB, 256, 0, stream>>>(ebuf, bbase, epk, offs, dcnt);
  deg_scan<<<1, 64, 0, stream>>>(dcnt, dcur);
  deg_order<<<(Nn + 255) / 256, 256, 0, stream>>>(offs, dcur, order, Nn);

  // Precompute
  const int pc_threads = 256 + 2560 + 114688 + 896 + 1024 + 16384 + Nn * 16;
  pp_cast<<<(pc_threads + 255) / 256, 256, 0, stream>>>(
      Wq, Wk, Wv, Wsk, bq, bk, bv, bsk, hemb, We, x, fw1, fb1, fw2, fb2,
      WcatT, Wcat, bcat, epth, xh, fw1h, bfv, bzero, Nn);
  tr_fw2<<<dim3(8, 2, 2), 256, 0, stream>>>(fw2, fw2Th);
  pp_bmid<<<4, 256, 0, stream>>>(bfv, Wcat, bcat, bmid);
  wf_gemm<<<dim3(1, 1, 2), 256, 0, stream>>>(fw1h, fw2Th, Wf, Wfh, BtMid);
  gemm_tn_f16<false, false, true><<<dim3(7, 1), 256, 0, stream>>>(
      Wfh, WcatT, bzero, nullptr, 0, nullptr, 0, 0, BtMid + 16384, 128, 128, 896, 128);

  // Layer 0: QKVS0 = xh @ Wcat + bcat
  gemm_tn_f16<false, true, false><<<dim3(QW / 128, Nn / 128), 256, 0, stream>>>(
      xh, WcatT, bcat, nullptr, 0, QKVSh, 0, QW, nullptr, 0, Nn, QW, DD);
  node_attn_ln_kernel<<<Nn / 4, 256, 0, stream>>>(QKVSh, epth, xh, offs, epk, order,
                                                  lng, lnb, hln0, Nn);
  // Fused: [h1h (f16) | QKVS1 (f16)] = hln0 @ [Wf0 | Wf0@Wcat] + bmid
  gemm_tn_f16<true, true, false><<<dim3(1024 / 128, Nn / 128), 256, 0, stream>>>(
      hln0, BtMid, bmid, h1h, 128, QKVSh, 128, QW, nullptr, 0, Nn, 1024, DD);
  node_attn_ln_kernel<<<Nn / 4, 256, 0, stream>>>(QKVSh, epth, h1h, offs, epk, order,
                                                  lng + DD, lnb + DD, hln1, Nn);
  final_kernel<<<64, 128, 0, stream>>>(hln1, Wf, bfv, midx, (float*)d_out);
}